// Round 4
// baseline (32.113 us; speedup 1.0000x reference)
//
#include <hip/hip_runtime.h>

// IntrinsicLoss: out[b] = ||A_b w_b||^2, A_b built from X[b,0:6].
// Memory-bound streaming. v4 = v3 with clang ext_vector float4 so the
// nontemporal builtins compile (HIP_vector_type is a class, rejected).
// 4 rows/thread -> 6+4 dwordx4 nontemporal loads + one contiguous float4
// store per thread; no LDS; half the waves of v1/v2, deeper per-wave MLP.

typedef float f4 __attribute__((ext_vector_type(4)));

__device__ __forceinline__ float row_loss(float x0, float x1, float x2,
                                          float x3, float x4, float x5,
                                          float w0, float w1, float w2, float w3) {
    // row0 = [x0*x2 + x1*x3, x0 + x2, x1 + x3, 1]
    // row1 = [x0*x4 + x1*x5, x0 + x4, x1 + x5, 1]
    // row2 = [x2*x4 + x3*x5, x2 + x4, x3 + x5, 1]
    float r0 = fmaf(fmaf(x0, x2, x1 * x3), w0,
               fmaf(x0 + x2, w1, fmaf(x1 + x3, w2, w3)));
    float r1 = fmaf(fmaf(x0, x4, x1 * x5), w0,
               fmaf(x0 + x4, w1, fmaf(x1 + x5, w2, w3)));
    float r2 = fmaf(fmaf(x2, x4, x3 * x5), w0,
               fmaf(x2 + x4, w1, fmaf(x3 + x5, w2, w3)));
    return fmaf(r0, r0, fmaf(r1, r1, r2 * r2));
}

__global__ __launch_bounds__(256) void IntrinsicLoss_kernel(
    const f4* __restrict__ X4,   // X as f4[]; 6 per row-quad
    const f4* __restrict__ W4,   // W as f4[]; 4 per row-quad
    f4* __restrict__ out4,       // out as f4[]; 1 per row-quad
    int nquads, int ntail,
    const float* __restrict__ Xs,    // scalar views for the tail rows
    const float* __restrict__ Ws,
    float* __restrict__ outs)
{
    int idx = blockIdx.x * blockDim.x + threadIdx.x;
    if (idx < nquads) {
        const f4* xp = X4 + (size_t)idx * 6;
        const f4* wp = W4 + (size_t)idx * 4;
        f4 x0 = __builtin_nontemporal_load(xp + 0);
        f4 x1 = __builtin_nontemporal_load(xp + 1);
        f4 x2 = __builtin_nontemporal_load(xp + 2);
        f4 x3 = __builtin_nontemporal_load(xp + 3);
        f4 x4 = __builtin_nontemporal_load(xp + 4);
        f4 x5 = __builtin_nontemporal_load(xp + 5);
        f4 w0 = __builtin_nontemporal_load(wp + 0);
        f4 w1 = __builtin_nontemporal_load(wp + 1);
        f4 w2 = __builtin_nontemporal_load(wp + 2);
        f4 w3 = __builtin_nontemporal_load(wp + 3);

        float l0 = row_loss(x0.x, x0.y, x0.z, x0.w, x1.x, x1.y,
                            w0.x, w0.y, w0.z, w0.w);
        float l1 = row_loss(x1.z, x1.w, x2.x, x2.y, x2.z, x2.w,
                            w1.x, w1.y, w1.z, w1.w);
        float l2 = row_loss(x3.x, x3.y, x3.z, x3.w, x4.x, x4.y,
                            w2.x, w2.y, w2.z, w2.w);
        float l3 = row_loss(x4.z, x4.w, x5.x, x5.y, x5.z, x5.w,
                            w3.x, w3.y, w3.z, w3.w);

        f4 o = {l0, l1, l2, l3};
        __builtin_nontemporal_store(o, out4 + idx);
    } else {
        int tid = idx - nquads;
        if (tid < ntail) {
            int r = nquads * 4 + tid;   // leftover row, scalar path
            float l = row_loss(Xs[r * 6 + 0], Xs[r * 6 + 1], Xs[r * 6 + 2],
                               Xs[r * 6 + 3], Xs[r * 6 + 4], Xs[r * 6 + 5],
                               Ws[r * 4 + 0], Ws[r * 4 + 1], Ws[r * 4 + 2],
                               Ws[r * 4 + 3]);
            outs[r] = l;
        }
    }
}

extern "C" void kernel_launch(void* const* d_in, const int* in_sizes, int n_in,
                              void* d_out, int out_size, void* d_ws, size_t ws_size,
                              hipStream_t stream) {
    const float* X = (const float*)d_in[0];   // [B, 6] fp32
    const float* W = (const float*)d_in[1];   // [B, 4] fp32
    float* out = (float*)d_out;               // [B] fp32

    int B = in_sizes[0] / 6;
    int nquads = B / 4;
    int ntail = B - nquads * 4;
    int nthreads = nquads + ntail;
    int grid = (nthreads + 255) / 256;

    IntrinsicLoss_kernel<<<grid, 256, 0, stream>>>(
        (const f4*)X, (const f4*)W, (f4*)out,
        nquads, ntail, X, W, out);
}

// Round 5
// 19.047 us; speedup vs baseline: 1.6860x; 1.6860x over previous
//
#include <hip/hip_runtime.h>

// IntrinsicLoss: out[b] = ||A_b w_b||^2, A_b built from X[b,0:6].
// Memory-bound, L3-resident working set (92 MB < 256 MB Infinity Cache) --
// v4 proved nontemporal hints are poison here (-70%). v5 = v1's best-known
// access pattern (2 rows/thread, 3+2 dwordx4 cached loads, float2 store)
// + grid-stride: 1024 blocks x 256 thr, 4 pairs/thread. All blocks resident
// for the whole kernel (4 blocks/CU), 4 independent iterations/thread give
// the scheduler up to 20 outstanding loads to pipeline.

typedef float f4 __attribute__((ext_vector_type(4)));
typedef float f2 __attribute__((ext_vector_type(2)));

__device__ __forceinline__ float row_loss(float x0, float x1, float x2,
                                          float x3, float x4, float x5,
                                          float w0, float w1, float w2, float w3) {
    // row0 = [x0*x2 + x1*x3, x0 + x2, x1 + x3, 1]
    // row1 = [x0*x4 + x1*x5, x0 + x4, x1 + x5, 1]
    // row2 = [x2*x4 + x3*x5, x2 + x4, x3 + x5, 1]
    float r0 = fmaf(fmaf(x0, x2, x1 * x3), w0,
               fmaf(x0 + x2, w1, fmaf(x1 + x3, w2, w3)));
    float r1 = fmaf(fmaf(x0, x4, x1 * x5), w0,
               fmaf(x0 + x4, w1, fmaf(x1 + x5, w2, w3)));
    float r2 = fmaf(fmaf(x2, x4, x3 * x5), w0,
               fmaf(x2 + x4, w1, fmaf(x3 + x5, w2, w3)));
    return fmaf(r0, r0, fmaf(r1, r1, r2 * r2));
}

__global__ __launch_bounds__(256) void IntrinsicLoss_kernel(
    const f4* __restrict__ X4,   // X as f4[]; 3 per row-pair
    const f4* __restrict__ W4,   // W as f4[]; 2 per row-pair
    f2* __restrict__ out2,       // out as f2[]; 1 per row-pair
    int npairs, int odd, int stride,
    const float* __restrict__ Xs,    // scalar views for the odd tail row
    const float* __restrict__ Ws,
    float* __restrict__ outs)
{
    int idx = blockIdx.x * blockDim.x + threadIdx.x;

    #pragma unroll 4
    for (int p = idx; p < npairs; p += stride) {
        f4 a  = X4[(size_t)p * 3 + 0];  // xA0 xA1 xA2 xA3
        f4 c1 = X4[(size_t)p * 3 + 1];  // xA4 xA5 xB0 xB1
        f4 c2 = X4[(size_t)p * 3 + 2];  // xB2 xB3 xB4 xB5
        f4 wa = W4[(size_t)p * 2 + 0];
        f4 wb = W4[(size_t)p * 2 + 1];
        float la = row_loss(a.x, a.y, a.z, a.w, c1.x, c1.y,
                            wa.x, wa.y, wa.z, wa.w);
        float lb = row_loss(c1.z, c1.w, c2.x, c2.y, c2.z, c2.w,
                            wb.x, wb.y, wb.z, wb.w);
        f2 o = {la, lb};
        out2[p] = o;
    }

    if (odd && idx == 0) {
        int r = 2 * npairs;   // last (odd) row, scalar path
        float l = row_loss(Xs[r * 6 + 0], Xs[r * 6 + 1], Xs[r * 6 + 2],
                           Xs[r * 6 + 3], Xs[r * 6 + 4], Xs[r * 6 + 5],
                           Ws[r * 4 + 0], Ws[r * 4 + 1], Ws[r * 4 + 2],
                           Ws[r * 4 + 3]);
        outs[r] = l;
    }
}

extern "C" void kernel_launch(void* const* d_in, const int* in_sizes, int n_in,
                              void* d_out, int out_size, void* d_ws, size_t ws_size,
                              hipStream_t stream) {
    const float* X = (const float*)d_in[0];   // [B, 6] fp32
    const float* W = (const float*)d_in[1];   // [B, 4] fp32
    float* out = (float*)d_out;               // [B] fp32

    int B = in_sizes[0] / 6;
    int npairs = B / 2;
    int odd = B & 1;

    const int BLOCKS = 1024;            // 4 blocks/CU, all resident
    const int THREADS = 256;
    int stride = BLOCKS * THREADS;

    IntrinsicLoss_kernel<<<BLOCKS, THREADS, 0, stream>>>(
        (const f4*)X, (const f4*)W, (f2*)out,
        npairs, odd, stride, X, W, out);
}